// Round 7
// baseline (132.551 us; speedup 1.0000x reference)
//
#include <hip/hip_runtime.h>

typedef unsigned long long u64;
typedef int i32x4 __attribute__((ext_vector_type(4)));

#define HW    3136      // 56*56 ; 3136 % 64 == 0 -> tiles never straddle images
#define CIN   256
#define CMID  768
#define EPSV  1e-5

// ---------------------------------------------------------------------------
// prep: weights -> i8 sign matrices (-1/0/+1); BN folded to (inv, c) f32 pairs:
//   y_bn = y*inv + c,  inv = g*rsqrt(v+eps), c = b - m*inv
// ---------------------------------------------------------------------------
__global__ __launch_bounds__(64) void prep_kernel(
    const float* __restrict__ w1, const float* __restrict__ w2,
    const float* __restrict__ g1, const float* __restrict__ b1,
    const float* __restrict__ m1, const float* __restrict__ v1,
    const float* __restrict__ g2, const float* __restrict__ b2,
    const float* __restrict__ m2, const float* __restrict__ v2,
    char* __restrict__ w1b, char* __restrict__ w2b,
    float2* __restrict__ ic1, float2* __restrict__ ic2)
{
  int blk = blockIdx.x, lane = threadIdx.x;
  if (blk < 1536) {                       // 2 x 196608 weight elements, 4/thread
    const float* src = (blk < 768) ? w1 : w2;
    char*        dst = (blk < 768) ? w1b : w2b;
    int idx  = ((blk < 768) ? blk : blk - 768) * 64 + lane;
    int base = idx * 4;
    unsigned d = 0;
    #pragma unroll
    for (int j = 0; j < 4; ++j) {
      float v = src[base + j];
      unsigned s = (v < 0.f) ? 0xFFu : (v > 0.f ? 1u : 0u);
      d |= s << (8 * j);
    }
    *(unsigned*)(dst + base) = d;
  } else {
    int i = (blk - 1536) * 64 + lane;     // 1024 BN entries
    if (i < CMID) {
      double inv = (double)g1[i] / sqrt((double)v1[i] + EPSV);
      float2 o; o.x = (float)inv;
      o.y = (float)((double)b1[i] - (double)m1[i] * inv);
      ic1[i] = o;
    } else {
      int j = i - CMID;
      double inv = (double)g2[j] / sqrt((double)v2[j] + EPSV);
      float2 o; o.x = (float)inv;
      o.y = (float)((double)b2[j] - (double)m2[j] * inv);
      ic2[j] = o;
    }
  }
}

// ---------------------------------------------------------------------------
// main: 1568 blocks x 256 thr (4 waves), 64-pixel tile, both layers on MFMA.
// sBx/sY layouts are [px][k] i8 with XOR swizzle (byte ^= (px&15)<<4 on 16B
// slots) -> all ds_read_b128 fragment reads conflict-free.
// L1: wave w rows [192w,+192) in 4 chunks of 48 (3 M-tiles); B-frags for the
//     whole K=256 hoisted into regs (16 x i32x4), A-frags from global (L2$).
// L2: wave w rows [64w,+64) single chunk (4 M-tiles), K=768 from sY.
// sign(0)=0 handled natively by the 0 byte in i8 MFMA — no special path.
// ---------------------------------------------------------------------------
__global__ __launch_bounds__(256, 2) void bnn_kernel(
    const float* __restrict__ x,
    const char* __restrict__ w1b, const char* __restrict__ w2b,
    const float2* __restrict__ ic1, const float2* __restrict__ ic2,
    float* __restrict__ out)
{
  __shared__ __align__(16) char sBx[64 * 256];   // 16 KB
  __shared__ __align__(16) char sY[64 * 768];    // 48 KB  (total 64 KB)

  int t    = threadIdx.x;
  int w    = t >> 6;
  int lane = t & 63;
  int l15  = lane & 15;
  int g4   = lane >> 4;
  int swz  = l15 << 4;                 // == (px&15)<<4 whenever px&15 == l15

  int px0 = blockIdx.x * 64;           // 1568*64 == 100352 exactly
  int b   = px0 / HW;
  int hw0 = px0 - b * HW;
  const float* xb = x   + (size_t)b * (CIN * HW) + hw0;
  float*       ob = out + (size_t)b * (CIN * HW) + hw0;

  // ---- pack: thread packs px=lane, chans [64w,64w+64) -> i8 {-1,0,1} ----
  {
    const float* xp = xb + lane + (size_t)(w << 6) * HW;
    int rowbase = lane * 256 + (w << 6);
    int pswz    = (lane & 15) << 4;
    #pragma unroll
    for (int j = 0; j < 4; ++j) {      // 4 x b128 (16 chans each)
      unsigned d[4];
      #pragma unroll
      for (int q = 0; q < 4; ++q) {
        unsigned dv = 0;
        #pragma unroll
        for (int bb = 0; bb < 4; ++bb) {
          int c = j * 16 + q * 4 + bb;
          unsigned u = __float_as_uint(xp[(size_t)c * HW]);
          unsigned s = ((u + u) == 0u) ? 0u : (((int)u < 0) ? 0xFFu : 1u);
          dv |= s << (8 * bb);
        }
        d[q] = dv;
      }
      i32x4 v; v.x = (int)d[0]; v.y = (int)d[1]; v.z = (int)d[2]; v.w = (int)d[3];
      *(i32x4*)&sBx[(rowbase + j * 16) ^ pswz] = v;
    }
  }
  __syncthreads();

  // ---- layer 1: B-frags (whole K) hoisted, 4 M-chunks of 48 rows ----
  i32x4 bfa[4][4];                     // [ks][n]
  #pragma unroll
  for (int ks = 0; ks < 4; ++ks) {
    int k0 = ks * 64 + g4 * 16;
    #pragma unroll
    for (int n = 0; n < 4; ++n) {
      int px = n * 16 + l15;
      bfa[ks][n] = *(const i32x4*)&sBx[(px * 256 + k0) ^ swz];
    }
  }

  int wrow = w * 192;
  #pragma unroll 1
  for (int ch = 0; ch < 4; ++ch) {
    int rbase = wrow + ch * 48;
    i32x4 acc[3][4];
    #pragma unroll
    for (int m = 0; m < 3; ++m)
      #pragma unroll
      for (int n = 0; n < 4; ++n) acc[m][n] = (i32x4)0;

    #pragma unroll
    for (int ks = 0; ks < 4; ++ks) {
      int k0 = ks * 64 + g4 * 16;
      i32x4 af[3];
      #pragma unroll
      for (int m = 0; m < 3; ++m) {
        int row = rbase + m * 16 + l15;
        af[m] = *(const i32x4*)&w1b[(size_t)row * 256 + k0];
      }
      #pragma unroll
      for (int m = 0; m < 3; ++m)
        #pragma unroll
        for (int n = 0; n < 4; ++n)
          acc[m][n] = __builtin_amdgcn_mfma_i32_16x16x64_i8(
              af[m], bfa[ks][n], acc[m][n], 0, 0, 0);
    }

    // epilogue: BN-threshold -> i8 sign bytes into sY (1 b32/lane/tile)
    #pragma unroll
    for (int m = 0; m < 3; ++m) {
      int r0 = rbase + m * 16 + g4 * 4;
      float2 c0 = ic1[r0], c1 = ic1[r0 + 1], c2 = ic1[r0 + 2], c3 = ic1[r0 + 3];
      #pragma unroll
      for (int n = 0; n < 4; ++n) {
        int px = n * 16 + l15;
        float y0 = fmaf((float)acc[m][n].x, c0.x, c0.y);
        float y1 = fmaf((float)acc[m][n].y, c1.x, c1.y);
        float y2 = fmaf((float)acc[m][n].z, c2.x, c2.y);
        float y3 = fmaf((float)acc[m][n].w, c3.x, c3.y);
        unsigned dv =
            (unsigned)(y0 < 0.f ? 0xFFu : (y0 > 0.f ? 1u : 0u))
          | ((unsigned)(y1 < 0.f ? 0xFFu : (y1 > 0.f ? 1u : 0u)) << 8)
          | ((unsigned)(y2 < 0.f ? 0xFFu : (y2 > 0.f ? 1u : 0u)) << 16)
          | ((unsigned)(y3 < 0.f ? 0xFFu : (y3 > 0.f ? 1u : 0u)) << 24);
        *(unsigned*)&sY[(px * 768 + r0) ^ swz] = dv;
      }
    }
  }
  __syncthreads();

  // ---- layer 2: wave rows [64w,+64), K=768, BN + residual + store ----
  {
    int rbase = w << 6;
    i32x4 acc[4][4];
    #pragma unroll
    for (int m = 0; m < 4; ++m)
      #pragma unroll
      for (int n = 0; n < 4; ++n) acc[m][n] = (i32x4)0;

    #pragma unroll 4
    for (int ks = 0; ks < 12; ++ks) {
      int k0 = ks * 64 + g4 * 16;
      i32x4 bf[4];
      #pragma unroll
      for (int n = 0; n < 4; ++n) {
        int px = n * 16 + l15;
        bf[n] = *(const i32x4*)&sY[(px * 768 + k0) ^ swz];
      }
      i32x4 af[4];
      #pragma unroll
      for (int m = 0; m < 4; ++m) {
        int row = rbase + m * 16 + l15;
        af[m] = *(const i32x4*)&w2b[(size_t)row * 768 + k0];
      }
      #pragma unroll
      for (int m = 0; m < 4; ++m)
        #pragma unroll
        for (int n = 0; n < 4; ++n)
          acc[m][n] = __builtin_amdgcn_mfma_i32_16x16x64_i8(
              af[m], bf[n], acc[m][n], 0, 0, 0);
    }

    #pragma unroll
    for (int m = 0; m < 4; ++m) {
      int r0 = rbase + m * 16 + g4 * 4;
      float2 c0 = ic2[r0], c1 = ic2[r0 + 1], c2 = ic2[r0 + 2], c3 = ic2[r0 + 3];
      #pragma unroll
      for (int n = 0; n < 4; ++n) {
        int pxo = n * 16 + l15;
        const float* xq = xb + pxo;
        float*       oq = ob + pxo;
        size_t o0 = (size_t)r0 * HW;
        oq[o0]          = fmaf((float)acc[m][n].x, c0.x, c0.y) + xq[o0];
        oq[o0 + HW]     = fmaf((float)acc[m][n].y, c1.x, c1.y) + xq[o0 + HW];
        oq[o0 + 2 * HW] = fmaf((float)acc[m][n].z, c2.x, c2.y) + xq[o0 + 2 * HW];
        oq[o0 + 3 * HW] = fmaf((float)acc[m][n].w, c3.x, c3.y) + xq[o0 + 3 * HW];
      }
    }
  }
}

extern "C" void kernel_launch(void* const* d_in, const int* in_sizes, int n_in,
                              void* d_out, int out_size, void* d_ws, size_t ws_size,
                              hipStream_t stream) {
  const float* x  = (const float*)d_in[0];
  const float* w1 = (const float*)d_in[1];
  const float* w2 = (const float*)d_in[2];
  const float* g1 = (const float*)d_in[3];
  const float* b1 = (const float*)d_in[4];
  const float* m1 = (const float*)d_in[5];
  const float* v1 = (const float*)d_in[6];
  const float* g2 = (const float*)d_in[7];
  const float* b2 = (const float*)d_in[8];
  const float* m2 = (const float*)d_in[9];
  const float* v2 = (const float*)d_in[10];
  float* out = (float*)d_out;

  char*   w1b = (char*)d_ws;               // 196608 B
  char*   w2b = w1b + 196608;              // 196608 B
  float2* ic1 = (float2*)(w2b + 196608);   // 768 * 8 B
  float2* ic2 = ic1 + CMID;                // 256 * 8 B

  prep_kernel<<<1552, 64, 0, stream>>>(w1, w2, g1, b1, m1, v1,
                                       g2, b2, m2, v2, w1b, w2b, ic1, ic2);
  bnn_kernel<<<1568, 256, 0, stream>>>(x, w1b, w2b, ic1, ic2, out);
}

// Round 8
// 128.765 us; speedup vs baseline: 1.0294x; 1.0294x over previous
//
#include <hip/hip_runtime.h>

typedef unsigned long long u64;
typedef int i32x4 __attribute__((ext_vector_type(4)));

#define HW    3136      // 56*56 ; 3136 % 64 == 0 -> tiles never straddle images
#define CIN   256
#define CMID  768
#define EPSV  1e-5

// ---------------------------------------------------------------------------
// prep: weights -> i8 sign matrices (-1/0/+1); BN folded to (inv, c) f32 pairs:
//   y_bn = y*inv + c,  inv = g*rsqrt(v+eps), c = b - m*inv
// ---------------------------------------------------------------------------
__global__ __launch_bounds__(64) void prep_kernel(
    const float* __restrict__ w1, const float* __restrict__ w2,
    const float* __restrict__ g1, const float* __restrict__ b1,
    const float* __restrict__ m1, const float* __restrict__ v1,
    const float* __restrict__ g2, const float* __restrict__ b2,
    const float* __restrict__ m2, const float* __restrict__ v2,
    char* __restrict__ w1b, char* __restrict__ w2b,
    float2* __restrict__ ic1, float2* __restrict__ ic2)
{
  int blk = blockIdx.x, lane = threadIdx.x;
  if (blk < 1536) {                       // 2 x 196608 weight elements, 4/thread
    const float* src = (blk < 768) ? w1 : w2;
    char*        dst = (blk < 768) ? w1b : w2b;
    int idx  = ((blk < 768) ? blk : blk - 768) * 64 + lane;
    int base = idx * 4;
    unsigned d = 0;
    #pragma unroll
    for (int j = 0; j < 4; ++j) {
      float v = src[base + j];
      unsigned s = (v < 0.f) ? 0xFFu : (v > 0.f ? 1u : 0u);
      d |= s << (8 * j);
    }
    *(unsigned*)(dst + base) = d;
  } else {
    int i = (blk - 1536) * 64 + lane;     // 1024 BN entries
    if (i < CMID) {
      double inv = (double)g1[i] / sqrt((double)v1[i] + EPSV);
      float2 o; o.x = (float)inv;
      o.y = (float)((double)b1[i] - (double)m1[i] * inv);
      ic1[i] = o;
    } else {
      int j = i - CMID;
      double inv = (double)g2[j] / sqrt((double)v2[j] + EPSV);
      float2 o; o.x = (float)inv;
      o.y = (float)((double)b2[j] - (double)m2[j] * inv);
      ic2[j] = o;
    }
  }
}

// ---------------------------------------------------------------------------
// main: 1568 blocks x 256 thr (4 waves), 64-pixel tile, both layers on MFMA,
// now with explicit software pipelining:
//   L1: A-chunk (12 frags) double-buffered -> next chunk's global loads fly
//       under current chunk's MFMA + epilogue.
//   L2: 12 K-steps fully unrolled, A(global)+B(LDS) triple-buffered (2-deep).
// sign(0)=0 native in i8 MFMA. Swizzle ^(px&15)<<4 on 16B slots (as R7).
// ---------------------------------------------------------------------------
__global__ __launch_bounds__(256, 2) void bnn_kernel(
    const float* __restrict__ x,
    const char* __restrict__ w1b, const char* __restrict__ w2b,
    const float2* __restrict__ ic1, const float2* __restrict__ ic2,
    float* __restrict__ out)
{
  __shared__ __align__(16) char sBx[64 * 256];   // 16 KB
  __shared__ __align__(16) char sY[64 * 768];    // 48 KB  (total 64 KB)

  int t    = threadIdx.x;
  int w    = t >> 6;
  int lane = t & 63;
  int l15  = lane & 15;
  int g4   = lane >> 4;
  int swz  = l15 << 4;

  int px0 = blockIdx.x * 64;           // 1568*64 == 100352 exactly
  int b   = px0 / HW;
  int hw0 = px0 - b * HW;
  const float* xb = x   + (size_t)b * (CIN * HW) + hw0;
  float*       ob = out + (size_t)b * (CIN * HW) + hw0;

  // ---- pack: thread packs px=lane, chans [64w,64w+64) -> i8 {-1,0,1} ----
  {
    const float* xp = xb + lane + (size_t)(w << 6) * HW;
    int rowbase = lane * 256 + (w << 6);
    int pswz    = (lane & 15) << 4;
    #pragma unroll
    for (int j = 0; j < 4; ++j) {      // 4 x b128 (16 chans each)
      unsigned d[4];
      #pragma unroll
      for (int q = 0; q < 4; ++q) {
        unsigned dv = 0;
        #pragma unroll
        for (int bb = 0; bb < 4; ++bb) {
          int c = j * 16 + q * 4 + bb;
          unsigned u = __float_as_uint(xp[(size_t)c * HW]);
          unsigned s = ((u + u) == 0u) ? 0u : (((int)u < 0) ? 0xFFu : 1u);
          dv |= s << (8 * bb);
        }
        d[q] = dv;
      }
      i32x4 v; v.x = (int)d[0]; v.y = (int)d[1]; v.z = (int)d[2]; v.w = (int)d[3];
      *(i32x4*)&sBx[(rowbase + j * 16) ^ pswz] = v;
    }
  }
  __syncthreads();

  // ---- hoist B-fragments (whole K=256) ----
  i32x4 bfa[4][4];                     // [ks][n]
  #pragma unroll
  for (int ks = 0; ks < 4; ++ks) {
    int k0 = ks * 64 + g4 * 16;
    #pragma unroll
    for (int n = 0; n < 4; ++n)
      bfa[ks][n] = *(const i32x4*)&sBx[((n * 16 + l15) * 256 + k0) ^ swz];
  }

  int wrow = w * 192;

  // ---- layer 1: 4 chunks of 48 rows, A double-buffered ----
  i32x4 afA[3][4], afB[3][4];          // [m][ks]

#define LD1(BUF, CH)                                                          \
  _Pragma("unroll") for (int ks = 0; ks < 4; ++ks)                            \
  _Pragma("unroll") for (int m = 0; m < 3; ++m)                               \
    BUF[m][ks] = *(const i32x4*)&w1b[                                         \
        (size_t)(wrow + (CH) * 48 + m * 16 + l15) * 256 + ks * 64 + g4 * 16];

#define CH1(BUF, CH) {                                                        \
  i32x4 acc[3][4];                                                            \
  _Pragma("unroll") for (int m = 0; m < 3; ++m)                               \
  _Pragma("unroll") for (int n = 0; n < 4; ++n) acc[m][n] = (i32x4)0;         \
  _Pragma("unroll") for (int ks = 0; ks < 4; ++ks)                            \
  _Pragma("unroll") for (int m = 0; m < 3; ++m)                               \
  _Pragma("unroll") for (int n = 0; n < 4; ++n)                               \
    acc[m][n] = __builtin_amdgcn_mfma_i32_16x16x64_i8(                        \
        BUF[m][ks], bfa[ks][n], acc[m][n], 0, 0, 0);                          \
  _Pragma("unroll") for (int m = 0; m < 3; ++m) {                             \
    int r0 = wrow + (CH) * 48 + m * 16 + g4 * 4;                              \
    float2 c0 = ic1[r0], c1 = ic1[r0+1], c2 = ic1[r0+2], c3 = ic1[r0+3];      \
    _Pragma("unroll") for (int n = 0; n < 4; ++n) {                           \
      int px = n * 16 + l15;                                                  \
      float y0 = fmaf((float)acc[m][n].x, c0.x, c0.y);                        \
      float y1 = fmaf((float)acc[m][n].y, c1.x, c1.y);                        \
      float y2 = fmaf((float)acc[m][n].z, c2.x, c2.y);                        \
      float y3 = fmaf((float)acc[m][n].w, c3.x, c3.y);                        \
      unsigned dv =                                                           \
          (unsigned)(y0 < 0.f ? 0xFFu : (y0 > 0.f ? 1u : 0u))                 \
        | ((unsigned)(y1 < 0.f ? 0xFFu : (y1 > 0.f ? 1u : 0u)) << 8)          \
        | ((unsigned)(y2 < 0.f ? 0xFFu : (y2 > 0.f ? 1u : 0u)) << 16)         \
        | ((unsigned)(y3 < 0.f ? 0xFFu : (y3 > 0.f ? 1u : 0u)) << 24);        \
      *(unsigned*)&sY[(px * 768 + r0) ^ swz] = dv;                            \
    }                                                                         \
  }                                                                           \
}

  LD1(afA, 0);
  LD1(afB, 1);          // prefetch chunk 1 while chunk 0 computes
  CH1(afA, 0);
  LD1(afA, 2);          // prefetch chunk 2 under chunk 1
  CH1(afB, 1);
  LD1(afB, 3);          // prefetch chunk 3 under chunk 2
  CH1(afA, 2);
  CH1(afB, 3);
#undef LD1
#undef CH1
  __syncthreads();

  // ---- layer 2: wave rows [64w,+64), K=768, 12 steps, 2-deep prefetch ----
  {
    int rbase = w << 6;
    i32x4 acc[4][4];
    #pragma unroll
    for (int m = 0; m < 4; ++m)
      #pragma unroll
      for (int n = 0; n < 4; ++n) acc[m][n] = (i32x4)0;

    i32x4 afX[4], afY[4], afZ[4];
    i32x4 bfX[4], bfY[4], bfZ[4];

#define LDA2(BUF, KS)                                                         \
  _Pragma("unroll") for (int m = 0; m < 4; ++m)                               \
    BUF[m] = *(const i32x4*)&w2b[                                             \
        (size_t)(rbase + m * 16 + l15) * 768 + (KS) * 64 + g4 * 16];
#define LDB2(BUF, KS)                                                         \
  _Pragma("unroll") for (int n = 0; n < 4; ++n)                               \
    BUF[n] = *(const i32x4*)&sY[((n * 16 + l15) * 768 + (KS) * 64 + g4 * 16) ^ swz];
#define MM2(A, B)                                                             \
  _Pragma("unroll") for (int m = 0; m < 4; ++m)                               \
  _Pragma("unroll") for (int n = 0; n < 4; ++n)                               \
    acc[m][n] = __builtin_amdgcn_mfma_i32_16x16x64_i8(A[m], B[n], acc[m][n], 0, 0, 0);

    LDA2(afX, 0);  LDB2(bfX, 0);
    LDA2(afY, 1);  LDB2(bfY, 1);
    LDA2(afZ, 2);  LDB2(bfZ, 2);   MM2(afX, bfX);
    LDA2(afX, 3);  LDB2(bfX, 3);   MM2(afY, bfY);
    LDA2(afY, 4);  LDB2(bfY, 4);   MM2(afZ, bfZ);
    LDA2(afZ, 5);  LDB2(bfZ, 5);   MM2(afX, bfX);
    LDA2(afX, 6);  LDB2(bfX, 6);   MM2(afY, bfY);
    LDA2(afY, 7);  LDB2(bfY, 7);   MM2(afZ, bfZ);
    LDA2(afZ, 8);  LDB2(bfZ, 8);   MM2(afX, bfX);
    LDA2(afX, 9);  LDB2(bfX, 9);   MM2(afY, bfY);
    LDA2(afY, 10); LDB2(bfY, 10);  MM2(afZ, bfZ);
    LDA2(afZ, 11); LDB2(bfZ, 11);  MM2(afX, bfX);
    MM2(afY, bfY);
    MM2(afZ, bfZ);
#undef LDA2
#undef LDB2
#undef MM2

    // epilogue: BN + residual + store
    #pragma unroll
    for (int m = 0; m < 4; ++m) {
      int r0 = rbase + m * 16 + g4 * 4;
      float2 c0 = ic2[r0], c1 = ic2[r0 + 1], c2 = ic2[r0 + 2], c3 = ic2[r0 + 3];
      #pragma unroll
      for (int n = 0; n < 4; ++n) {
        int pxo = n * 16 + l15;
        const float* xq = xb + pxo;
        float*       oq = ob + pxo;
        size_t o0 = (size_t)r0 * HW;
        oq[o0]          = fmaf((float)acc[m][n].x, c0.x, c0.y) + xq[o0];
        oq[o0 + HW]     = fmaf((float)acc[m][n].y, c1.x, c1.y) + xq[o0 + HW];
        oq[o0 + 2 * HW] = fmaf((float)acc[m][n].z, c2.x, c2.y) + xq[o0 + 2 * HW];
        oq[o0 + 3 * HW] = fmaf((float)acc[m][n].w, c3.x, c3.y) + xq[o0 + 3 * HW];
      }
    }
  }
}

extern "C" void kernel_launch(void* const* d_in, const int* in_sizes, int n_in,
                              void* d_out, int out_size, void* d_ws, size_t ws_size,
                              hipStream_t stream) {
  const float* x  = (const float*)d_in[0];
  const float* w1 = (const float*)d_in[1];
  const float* w2 = (const float*)d_in[2];
  const float* g1 = (const float*)d_in[3];
  const float* b1 = (const float*)d_in[4];
  const float* m1 = (const float*)d_in[5];
  const float* v1 = (const float*)d_in[6];
  const float* g2 = (const float*)d_in[7];
  const float* b2 = (const float*)d_in[8];
  const float* m2 = (const float*)d_in[9];
  const float* v2 = (const float*)d_in[10];
  float* out = (float*)d_out;

  char*   w1b = (char*)d_ws;               // 196608 B
  char*   w2b = w1b + 196608;              // 196608 B
  float2* ic1 = (float2*)(w2b + 196608);   // 768 * 8 B
  float2* ic2 = ic1 + CMID;                // 256 * 8 B

  prep_kernel<<<1552, 64, 0, stream>>>(w1, w2, g1, b1, m1, v1,
                                       g2, b2, m2, v2, w1b, w2b, ic1, ic2);
  bnn_kernel<<<1568, 256, 0, stream>>>(x, w1b, w2b, ic1, ic2, out);
}